// Round 3
// baseline (905.354 us; speedup 1.0000x reference)
//
#include <hip/hip_runtime.h>
#include <stdint.h>

// ---------- bf16 helpers (OCP bf16 == high 16 bits of f32) ----------
__device__ __forceinline__ float bf2f(unsigned short h) {
  union { uint32_t u; float f; } v; v.u = ((uint32_t)h) << 16; return v.f;
}
__device__ __forceinline__ unsigned short f2bf(float f) {
  union { float f; uint32_t u; } v; v.f = f;
  uint32_t u = v.u;
  u += 0x7FFFu + ((u >> 16) & 1u);   // round-to-nearest-even
  return (unsigned short)(u >> 16);
}

typedef __attribute__((ext_vector_type(8))) short short8;   // 8 bf16 (4 VGPRs)
typedef __attribute__((ext_vector_type(4))) float floatx4;  // MFMA C/D

// ---------- dtype probe ----------
// flags[0] = 1 if float inputs are fp32 (else bf16)
// flags[1] = 1 if edge_index is int64 (else int32)
__global__ void bgcn_probe(const uint32_t* __restrict__ xw,
                           const uint32_t* __restrict__ iw,
                           int* __restrict__ flags) {
  if (threadIdx.x == 0 && blockIdx.x == 0) {
    int hits = 0;
    for (int i = 0; i < 256; ++i) {
      uint32_t b = (xw[i] >> 8) & 0x7F;   // bf16-pair: exp[7:1] of N(0,1) low element
      if (b >= 0x38 && b <= 0x41) hits++;
    }
    flags[0] = (hits < 128) ? 1 : 0;      // random mantissa bits => fp32
    int nz = 0;
    for (int i = 1; i < 128; i += 2) nz += (iw[i] != 0);
    flags[1] = (nz == 0) ? 1 : 0;         // all odd words zero => int64
  }
}

// ---------- canonicalization ----------
__global__ void bgcn_cvt_f(const void* __restrict__ src, unsigned short* __restrict__ dst,
                           int n, const int* __restrict__ flags) {
  int i = blockIdx.x * 256 + threadIdx.x;
  if (i >= n) return;
  if (flags[0]) dst[i] = f2bf(((const float*)src)[i]);
  else          dst[i] = ((const unsigned short*)src)[i];
}
__global__ void bgcn_cvt_i(const void* __restrict__ src, int* __restrict__ dst,
                           int n, const int* __restrict__ flags) {
  int i = blockIdx.x * 256 + threadIdx.x;
  if (i >= n) return;
  if (flags[1]) dst[i] = (int)((const long long*)src)[i];
  else          dst[i] = ((const int*)src)[i];
}

// ---------- degree / normalization ----------
__global__ void bgcn_init_deg(float* __restrict__ deg, int n) {
  int i = blockIdx.x * 256 + threadIdx.x;
  if (i < n) deg[i] = 1.0f;   // self-loop weight 1
}
__global__ void bgcn_deg(const int* __restrict__ col, const unsigned short* __restrict__ ew,
                         float* __restrict__ deg, int E) {
  int e = blockIdx.x * 256 + threadIdx.x;
  if (e < E) atomicAdd(&deg[col[e]], bf2f(ew[e]));
}
__global__ void bgcn_dis(const float* __restrict__ deg, float* __restrict__ dis, int n) {
  int i = blockIdx.x * 256 + threadIdx.x;
  if (i < n) dis[i] = rsqrtf(deg[i]);   // deg >= 1 always
}

// ---------- CSR build: histogram + scan + scatter ----------
__global__ void bgcn_hist(const int* __restrict__ col, int* __restrict__ counts, int E) {
  int e = blockIdx.x * 256 + threadIdx.x;
  if (e < E) atomicAdd(&counts[col[e]], 1);
}
__global__ void bgcn_scan_block(const int* __restrict__ counts, int* __restrict__ rowptr,
                                int* __restrict__ blocksum, int n) {
  __shared__ int buf[1024];
  int gid = blockIdx.x * 1024 + threadIdx.x;
  int v = (gid < n) ? counts[gid] : 0;
  buf[threadIdx.x] = v;
  __syncthreads();
  for (int off = 1; off < 1024; off <<= 1) {
    int x = (threadIdx.x >= off) ? buf[threadIdx.x - off] : 0;
    __syncthreads();
    buf[threadIdx.x] += x;
    __syncthreads();
  }
  if (gid < n) rowptr[gid + 1] = buf[threadIdx.x];
  if (threadIdx.x == 1023) blocksum[blockIdx.x] = buf[1023];
}
__global__ void bgcn_scan_tops(int* __restrict__ blocksum, int nb) {
  if (threadIdx.x == 0 && blockIdx.x == 0) {
    int acc = 0;
    for (int i = 0; i < nb; ++i) { int v = blocksum[i]; blocksum[i] = acc; acc += v; }
  }
}
__global__ void bgcn_scan_add(int* __restrict__ rowptr, const int* __restrict__ blocksum, int n) {
  int gid = blockIdx.x * 1024 + threadIdx.x;
  if (gid < n) rowptr[gid + 1] += blocksum[blockIdx.x];
  if (gid == 0) rowptr[0] = 0;
}
__global__ void bgcn_scatter(const int* __restrict__ row, const int* __restrict__ col,
                             const unsigned short* __restrict__ ew,
                             const float* __restrict__ dis,
                             const int* __restrict__ rowptr, int* __restrict__ fill,
                             int* __restrict__ esrc, float* __restrict__ enorm, int E) {
  int e = blockIdx.x * 256 + threadIdx.x;
  if (e >= E) return;
  int r = row[e], c = col[e];
  int pos = rowptr[c] + atomicAdd(&fill[c], 1);
  esrc[pos]  = r;
  enorm[pos] = dis[r] * bf2f(ew[e]) * dis[c];
}

// ---------- bf16 MFMA GEMM: C[MxN] = A[MxK] @ B[KxN] ----------
// A raw fp32 or bf16 (a_probe=1: flags[0] decides; 0: bf16). B,C bf16.
// Block 256 (4 waves), tile 64x64, BK=32, LDS stride 40 (<=2-way bank alias: free).
#define LDS_STRIDE 40
__global__ __launch_bounds__(256) void bgcn_gemm(
    const void* __restrict__ Araw, int a_probe, const int* __restrict__ flags,
    const unsigned short* __restrict__ B,
    unsigned short* __restrict__ C,
    int M, int N, int K) {
  __shared__ unsigned short Abuf[64 * LDS_STRIDE];  // [m][k]
  __shared__ unsigned short Bbuf[64 * LDS_STRIDE];  // [n][k] (B transposed)
  const bool a_fp32 = a_probe && flags[0];
  int t = threadIdx.x;
  int wave = t >> 6, lane = t & 63;
  int m0 = blockIdx.x * 64;
  int n0 = blockIdx.y * 64;

  floatx4 acc[4];
  #pragma unroll
  for (int i = 0; i < 4; ++i)
    #pragma unroll
    for (int j = 0; j < 4; ++j) acc[i][j] = 0.0f;

  int a_m = t >> 2;            // 0..63
  int a_k = (t & 3) * 8;       // 0,8,16,24
  int b_n = t & 63;            // 0..63
  int b_ks = (t >> 6) * 8;     // 0,8,16,24

  int fr = lane & 15;          // m (or n) within 16-tile
  int fk = (lane >> 4) * 8;    // k offset of this quad

  for (int k0 = 0; k0 < K; k0 += 32) {
    uint4 av = make_uint4(0, 0, 0, 0);
    if (m0 + a_m < M) {
      if (a_fp32) {
        const float* Af = (const float*)Araw + (size_t)(m0 + a_m) * K + k0 + a_k;
        float4 f0 = *(const float4*)Af;
        float4 f1 = *(const float4*)(Af + 4);
        av.x = (uint32_t)f2bf(f0.x) | ((uint32_t)f2bf(f0.y) << 16);
        av.y = (uint32_t)f2bf(f0.z) | ((uint32_t)f2bf(f0.w) << 16);
        av.z = (uint32_t)f2bf(f1.x) | ((uint32_t)f2bf(f1.y) << 16);
        av.w = (uint32_t)f2bf(f1.z) | ((uint32_t)f2bf(f1.w) << 16);
      } else {
        av = *(const uint4*)((const unsigned short*)Araw + (size_t)(m0 + a_m) * K + k0 + a_k);
      }
    }
    *(uint4*)(Abuf + a_m * LDS_STRIDE + a_k) = av;

    uint4 bv;
    unsigned short* bp = (unsigned short*)&bv;
    #pragma unroll
    for (int j = 0; j < 8; ++j)
      bp[j] = B[(size_t)(k0 + b_ks + j) * N + n0 + b_n];
    *(uint4*)(Bbuf + b_n * LDS_STRIDE + b_ks) = bv;
    __syncthreads();

    short8 afrag = *(const short8*)(Abuf + (wave * 16 + fr) * LDS_STRIDE + fk);
    #pragma unroll
    for (int nt = 0; nt < 4; ++nt) {
      short8 bfrag = *(const short8*)(Bbuf + (nt * 16 + fr) * LDS_STRIDE + fk);
      acc[nt] = __builtin_amdgcn_mfma_f32_16x16x32_bf16(afrag, bfrag, acc[nt], 0, 0, 0);
    }
    __syncthreads();
  }

  // D: col=lane&15, row=(lane>>4)*4+r  [m89-verified]
  int col_l = lane & 15;
  int row_b = (lane >> 4) * 4;
  #pragma unroll
  for (int nt = 0; nt < 4; ++nt) {
    #pragma unroll
    for (int r = 0; r < 4; ++r) {
      int m = m0 + wave * 16 + row_b + r;
      if (m < M)
        C[(size_t)m * N + n0 + nt * 16 + col_l] = f2bf(acc[nt][r]);
    }
  }
}

// ---------- aggregation: out[c] = sum_e norm*H[src] + (1/deg_c)*H[c] + b, relu ----------
template <int VPL>
__device__ __forceinline__ void loadbf(const unsigned short* p, float* out) {
  if constexpr (VPL == 8) {
    uint4 v = *(const uint4*)p;
    uint32_t w0 = v.x, w1 = v.y, w2 = v.z, w3 = v.w;
    out[0] = bf2f((unsigned short)(w0 & 0xffff)); out[1] = bf2f((unsigned short)(w0 >> 16));
    out[2] = bf2f((unsigned short)(w1 & 0xffff)); out[3] = bf2f((unsigned short)(w1 >> 16));
    out[4] = bf2f((unsigned short)(w2 & 0xffff)); out[5] = bf2f((unsigned short)(w2 >> 16));
    out[6] = bf2f((unsigned short)(w3 & 0xffff)); out[7] = bf2f((unsigned short)(w3 >> 16));
  } else {
    uint32_t v = *(const uint32_t*)p;
    out[0] = bf2f((unsigned short)(v & 0xffff)); out[1] = bf2f((unsigned short)(v >> 16));
  }
}

template <int F>
__global__ __launch_bounds__(256) void bgcn_aggregate(
    const unsigned short* __restrict__ H,
    const int* __restrict__ rowptr,
    const int* __restrict__ esrc,
    const float* __restrict__ enorm,
    const float* __restrict__ dis,
    const unsigned short* __restrict__ bias,
    unsigned short* __restrict__ Out,
    int n_nodes) {
  constexpr int VPL = F / 64;
  int lane = threadIdx.x & 63;
  int c = blockIdx.x * 4 + (threadIdx.x >> 6);  // one wave per node
  if (c >= n_nodes) return;
  float acc[VPL];
  #pragma unroll
  for (int j = 0; j < VPL; ++j) acc[j] = 0.0f;

  int beg = rowptr[c], end = rowptr[c + 1];
  for (int e = beg; e < end; ++e) {
    int src = esrc[e];
    float w = enorm[e];
    float vals[VPL];
    loadbf<VPL>(H + (size_t)src * F + lane * VPL, vals);
    #pragma unroll
    for (int j = 0; j < VPL; ++j) acc[j] += w * vals[j];
  }
  float ds = dis[c];
  float wself = ds * ds;  // == 1/deg
  float vals[VPL];
  loadbf<VPL>(H + (size_t)c * F + lane * VPL, vals);
  #pragma unroll
  for (int j = 0; j < VPL; ++j) {
    float v = acc[j] + wself * vals[j] + bf2f(bias[lane * VPL + j]);
    Out[(size_t)c * F + lane * VPL + j] = f2bf(fmaxf(v, 0.0f));
  }
}

// ---------- FC(128->14) + sigmoid -> FP32 output ----------
__global__ __launch_bounds__(256) void bgcn_fc_sigmoid(
    const unsigned short* __restrict__ X,
    const unsigned short* __restrict__ W,
    const unsigned short* __restrict__ b,
    float* __restrict__ out,              // fp32! (reference output dtype)
    int n_nodes) {
  __shared__ float Ws[128 * 14];
  __shared__ float bs[14];
  for (int i = threadIdx.x; i < 128 * 14; i += 256) Ws[i] = bf2f(W[i]);
  if (threadIdx.x < 14) bs[threadIdx.x] = bf2f(b[threadIdx.x]);
  __syncthreads();
  int node = blockIdx.x * 256 + threadIdx.x;
  if (node >= n_nodes) return;
  float acc[14];
  #pragma unroll
  for (int c = 0; c < 14; ++c) acc[c] = bs[c];
  const unsigned short* xp = X + (size_t)node * 128;
  for (int k8 = 0; k8 < 16; ++k8) {
    float xv[8];
    loadbf<8>(xp + k8 * 8, xv);
    #pragma unroll
    for (int j = 0; j < 8; ++j) {
      int k = k8 * 8 + j;
      #pragma unroll
      for (int c = 0; c < 14; ++c) acc[c] = fmaf(xv[j], Ws[k * 14 + c], acc[c]);
    }
  }
  float* op = out + (size_t)node * 14;
  #pragma unroll
  for (int c = 0; c < 14; ++c)
    op[c] = 1.0f / (1.0f + __expf(-acc[c]));
}

// ---------- launch ----------
static inline void* wsa(char*& p, size_t bytes) {
  void* r = p;
  p += (bytes + 255) & ~(size_t)255;
  return r;
}

extern "C" void kernel_launch(void* const* d_in, const int* in_sizes, int n_in,
                              void* d_out, int out_size, void* d_ws, size_t ws_size,
                              hipStream_t stream) {
  const void* Xr   = d_in[0];   // [N,1024] fp32 (probed; bf16 also handled)
  const void* EIr  = d_in[1];   // [2,E] int64 (probed; int32 also handled)
  const void* EWr  = d_in[2];   // [E]
  const void* W1r  = d_in[3];   // [1024,512]
  const void* b1r  = d_in[4];
  const void* W2r  = d_in[5];   // [512,128]
  const void* b2r  = d_in[6];
  const void* Wfcr = d_in[7];   // [128,14]
  const void* bfcr = d_in[8];
  float* out = (float*)d_out;   // [N,14] fp32

  const int N = in_sizes[0] / 1024;   // 50000
  const int E = in_sizes[2];          // 800000

  char* p = (char*)d_ws;
  unsigned short* bufA = (unsigned short*)wsa(p, (size_t)N * 512 * 2);  // H1; later H2+X3
  unsigned short* bufB = (unsigned short*)wsa(p, (size_t)N * 512 * 2);  // X2
  float* deg      = (float*)wsa(p, (size_t)N * 4);
  float* dis      = (float*)wsa(p, (size_t)N * 4);
  int*   counts   = (int*)wsa(p, (size_t)N * 4);
  int*   rowptr   = (int*)wsa(p, (size_t)(N + 1) * 4);
  int*   blocksum = (int*)wsa(p, 256 * 4);
  int*   fill     = (int*)wsa(p, (size_t)N * 4);
  int*   esrc     = (int*)wsa(p, (size_t)E * 4);
  float* enorm    = (float*)wsa(p, (size_t)E * 4);
  int*   eidx     = (int*)wsa(p, (size_t)2 * E * 4);   // canonical int32 [2,E]
  unsigned short* ewb  = (unsigned short*)wsa(p, (size_t)E * 2);
  unsigned short* W1c  = (unsigned short*)wsa(p, (size_t)1024 * 512 * 2);
  unsigned short* W2c  = (unsigned short*)wsa(p, (size_t)512 * 128 * 2);
  unsigned short* b1c  = (unsigned short*)wsa(p, 512 * 2);
  unsigned short* b2c  = (unsigned short*)wsa(p, 128 * 2);
  unsigned short* Wfcc = (unsigned short*)wsa(p, 128 * 14 * 2);
  unsigned short* bfcc = (unsigned short*)wsa(p, 16 * 2);
  int* flags      = (int*)wsa(p, 2 * 4);

  unsigned short* H1 = bufA;
  unsigned short* X2 = bufB;
  unsigned short* H2 = bufA;                       // H1 dead by then
  unsigned short* X3 = bufA + (size_t)N * 128;     // disjoint from H2

  int gN = (N + 255) / 256;
  int gE = (E + 255) / 256;

  // dtype probe + canonicalization
  bgcn_probe<<<1, 64, 0, stream>>>((const uint32_t*)Xr, (const uint32_t*)EIr, flags);
  bgcn_cvt_i<<<(2 * E + 255) / 256, 256, 0, stream>>>(EIr, eidx, 2 * E, flags);
  bgcn_cvt_f<<<gE, 256, 0, stream>>>(EWr, ewb, E, flags);
  bgcn_cvt_f<<<(1024 * 512 + 255) / 256, 256, 0, stream>>>(W1r, W1c, 1024 * 512, flags);
  bgcn_cvt_f<<<(512 * 128 + 255) / 256, 256, 0, stream>>>(W2r, W2c, 512 * 128, flags);
  bgcn_cvt_f<<<2, 256, 0, stream>>>(b1r, b1c, 512, flags);
  bgcn_cvt_f<<<1, 256, 0, stream>>>(b2r, b2c, 128, flags);
  bgcn_cvt_f<<<7, 256, 0, stream>>>(Wfcr, Wfcc, 128 * 14, flags);
  bgcn_cvt_f<<<1, 64, 0, stream>>>(bfcr, bfcc, 14, flags);

  const int* rowp = eidx;        // sources
  const int* colp = eidx + E;    // targets

  hipMemsetAsync(counts, 0, (size_t)N * 4, stream);
  hipMemsetAsync(fill,   0, (size_t)N * 4, stream);

  bgcn_init_deg<<<gN, 256, 0, stream>>>(deg, N);
  bgcn_deg<<<gE, 256, 0, stream>>>(colp, ewb, deg, E);
  bgcn_dis<<<gN, 256, 0, stream>>>(deg, dis, N);
  bgcn_hist<<<gE, 256, 0, stream>>>(colp, counts, E);

  int nb = (N + 1023) / 1024;
  bgcn_scan_block<<<nb, 1024, 0, stream>>>(counts, rowptr, blocksum, N);
  bgcn_scan_tops<<<1, 64, 0, stream>>>(blocksum, nb);
  bgcn_scan_add<<<nb, 1024, 0, stream>>>(rowptr, blocksum, N);
  bgcn_scatter<<<gE, 256, 0, stream>>>(rowp, colp, ewb, dis, rowptr, fill, esrc, enorm, E);

  // layer 1: H1 = X @ W1 ; X2 = relu(agg(H1) + b1)
  dim3 g1((N + 63) / 64, 512 / 64);
  bgcn_gemm<<<g1, 256, 0, stream>>>(Xr, 1, flags, W1c, H1, N, 512, 1024);
  bgcn_aggregate<512><<<(N + 3) / 4, 256, 0, stream>>>(H1, rowptr, esrc, enorm, dis, b1c, X2, N);

  // layer 2: H2 = X2 @ W2 ; X3 = relu(agg(H2) + b2)
  dim3 g2((N + 63) / 64, 128 / 64);
  bgcn_gemm<<<g2, 256, 0, stream>>>(X2, 0, flags, W2c, H2, N, 128, 512);
  bgcn_aggregate<128><<<(N + 3) / 4, 256, 0, stream>>>(H2, rowptr, esrc, enorm, dis, b2c, X3, N);

  // FC + sigmoid (fp32 out)
  bgcn_fc_sigmoid<<<gN, 256, 0, stream>>>(X3, Wfcc, bfcc, out, N);
}

// Round 4
// 764.233 us; speedup vs baseline: 1.1847x; 1.1847x over previous
//
#include <hip/hip_runtime.h>
#include <stdint.h>

// ---------- bf16 helpers (OCP bf16 == high 16 bits of f32) ----------
__device__ __forceinline__ float bf2f(unsigned short h) {
  union { uint32_t u; float f; } v; v.u = ((uint32_t)h) << 16; return v.f;
}
__device__ __forceinline__ unsigned short f2bf(float f) {
  union { float f; uint32_t u; } v; v.f = f;
  uint32_t u = v.u;
  u += 0x7FFFu + ((u >> 16) & 1u);   // round-to-nearest-even
  return (unsigned short)(u >> 16);
}
__device__ __forceinline__ uint32_t pack2bf(float a, float b) {
  return (uint32_t)f2bf(a) | ((uint32_t)f2bf(b) << 16);
}

typedef __attribute__((ext_vector_type(8))) short short8;   // 8 bf16 (4 VGPRs)
typedef __attribute__((ext_vector_type(4))) float floatx4;  // MFMA C/D

// ---------- dtype probe ----------
// flags[0] = 1 if float inputs are fp32 (else bf16); flags[1] = 1 if edge_index int64
__global__ void bgcn_probe(const uint32_t* __restrict__ xw,
                           const uint32_t* __restrict__ iw,
                           int* __restrict__ flags) {
  if (threadIdx.x == 0 && blockIdx.x == 0) {
    int hits = 0;
    for (int i = 0; i < 256; ++i) {
      uint32_t b = (xw[i] >> 8) & 0x7F;
      if (b >= 0x38 && b <= 0x41) hits++;
    }
    flags[0] = (hits < 128) ? 1 : 0;
    int nz = 0;
    for (int i = 1; i < 128; i += 2) nz += (iw[i] != 0);
    flags[1] = (nz == 0) ? 1 : 0;
  }
}

// ---------- canonicalization ----------
__global__ void bgcn_cvt_f(const void* __restrict__ src, unsigned short* __restrict__ dst,
                           int n, const int* __restrict__ flags) {
  int i = blockIdx.x * 256 + threadIdx.x;
  if (i >= n) return;
  if (flags[0]) dst[i] = f2bf(((const float*)src)[i]);
  else          dst[i] = ((const unsigned short*)src)[i];
}
__global__ void bgcn_cvt_i(const void* __restrict__ src, int* __restrict__ dst,
                           int n, const int* __restrict__ flags) {
  int i = blockIdx.x * 256 + threadIdx.x;
  if (i >= n) return;
  if (flags[1]) dst[i] = (int)((const long long*)src)[i];
  else          dst[i] = ((const int*)src)[i];
}
// transpose + cvt: dst[N][K] bf16 <- src[K][N] (fp32 or bf16). K = 1<<kbits.
__global__ void bgcn_cvt_t(const void* __restrict__ src, unsigned short* __restrict__ dst,
                           int kbits, int N, int total, const int* __restrict__ flags) {
  int i = blockIdx.x * 256 + threadIdx.x;
  if (i >= total) return;
  int K = 1 << kbits;
  int n = i >> kbits;
  int k = i & (K - 1);
  size_t s = (size_t)k * N + n;
  if (flags[0]) dst[i] = f2bf(((const float*)src)[s]);
  else          dst[i] = ((const unsigned short*)src)[s];
}

// ---------- degree / normalization ----------
__global__ void bgcn_init_deg(float* __restrict__ deg, int n) {
  int i = blockIdx.x * 256 + threadIdx.x;
  if (i < n) deg[i] = 1.0f;
}
__global__ void bgcn_deg(const int* __restrict__ col, const unsigned short* __restrict__ ew,
                         float* __restrict__ deg, int E) {
  int e = blockIdx.x * 256 + threadIdx.x;
  if (e < E) atomicAdd(&deg[col[e]], bf2f(ew[e]));
}
__global__ void bgcn_dis(const float* __restrict__ deg, float* __restrict__ dis, int n) {
  int i = blockIdx.x * 256 + threadIdx.x;
  if (i < n) dis[i] = rsqrtf(deg[i]);
}

// ---------- CSR build ----------
__global__ void bgcn_hist(const int* __restrict__ col, int* __restrict__ counts, int E) {
  int e = blockIdx.x * 256 + threadIdx.x;
  if (e < E) atomicAdd(&counts[col[e]], 1);
}
__global__ void bgcn_scan_block(const int* __restrict__ counts, int* __restrict__ rowptr,
                                int* __restrict__ blocksum, int n) {
  __shared__ int buf[1024];
  int gid = blockIdx.x * 1024 + threadIdx.x;
  int v = (gid < n) ? counts[gid] : 0;
  buf[threadIdx.x] = v;
  __syncthreads();
  for (int off = 1; off < 1024; off <<= 1) {
    int x = (threadIdx.x >= off) ? buf[threadIdx.x - off] : 0;
    __syncthreads();
    buf[threadIdx.x] += x;
    __syncthreads();
  }
  if (gid < n) rowptr[gid + 1] = buf[threadIdx.x];
  if (threadIdx.x == 1023) blocksum[blockIdx.x] = buf[1023];
}
__global__ void bgcn_scan_tops(int* __restrict__ blocksum, int nb) {
  if (threadIdx.x == 0 && blockIdx.x == 0) {
    int acc = 0;
    for (int i = 0; i < nb; ++i) { int v = blocksum[i]; blocksum[i] = acc; acc += v; }
  }
}
__global__ void bgcn_scan_add(int* __restrict__ rowptr, const int* __restrict__ blocksum, int n) {
  int gid = blockIdx.x * 1024 + threadIdx.x;
  if (gid < n) rowptr[gid + 1] += blocksum[blockIdx.x];
  if (gid == 0) rowptr[0] = 0;
}
__global__ void bgcn_scatter(const int* __restrict__ row, const int* __restrict__ col,
                             const unsigned short* __restrict__ ew,
                             const float* __restrict__ dis,
                             const int* __restrict__ rowptr, int* __restrict__ fill,
                             int* __restrict__ esrc, float* __restrict__ enorm, int E) {
  int e = blockIdx.x * 256 + threadIdx.x;
  if (e >= E) return;
  int r = row[e], c = col[e];
  int pos = rowptr[c] + atomicAdd(&fill[c], 1);
  esrc[pos]  = r;
  enorm[pos] = dis[r] * bf2f(ew[e]) * dis[c];
}

// ---------- 128x128 MFMA GEMM: C[MxN] = A[MxK] @ Bt[NxK]^T ----------
// A raw fp32 or bf16 (a_probe=1: flags[0]; 0: bf16). Bt bf16 [N][K]. C bf16.
// 256 thr = 4 waves; wave computes 64x64 (4x4 of 16x16x32 mfma). BK=32.
// blockIdx.x = (mblk << nblk_bits) | nblk : n fastest so blocks sharing an
// A-stripe run adjacently -> A fetched ~once from HBM (L2/L3 reuse).
// LDS stride 40 shorts (80 B): fragment ds_read_b128 <=2-way bank alias (free, m136).
#define GST 40
__global__ __launch_bounds__(256, 2) void bgcn_gemm128(
    const void* __restrict__ Araw, int a_probe, const int* __restrict__ flags,
    const unsigned short* __restrict__ Bt,
    unsigned short* __restrict__ C,
    int M, int N, int K, int nblk_bits) {
  __shared__ unsigned short Abuf[128 * GST];
  __shared__ unsigned short Bbuf[128 * GST];
  const bool a_fp32 = a_probe && flags[0];
  int t = threadIdx.x;
  int wave = t >> 6, lane = t & 63;
  int bx = blockIdx.x;
  int nblk = bx & ((1 << nblk_bits) - 1);
  int mblk = bx >> nblk_bits;
  int m0 = mblk * 128, n0 = nblk * 128;

  floatx4 acc[4][4];
  #pragma unroll
  for (int i = 0; i < 4; ++i)
    #pragma unroll
    for (int j = 0; j < 4; ++j)
      #pragma unroll
      for (int r = 0; r < 4; ++r) acc[i][j][r] = 0.0f;

  // staging: thread t covers row = t>>1 (0..127), 16 k-elements at (t&1)*16
  int srow  = t >> 1;
  int skoff = (t & 1) * 16;
  int am = m0 + srow; if (am >= M) am = M - 1;            // clamp (store masked later)
  const float*          Af = (const float*)Araw          + (size_t)am * K + skoff;
  const unsigned short* Ah = (const unsigned short*)Araw + (size_t)am * K + skoff;
  const unsigned short* Bp = Bt + (size_t)(n0 + srow) * K + skoff;
  unsigned short* AL = Abuf + srow * GST + skoff;
  unsigned short* BL = Bbuf + srow * GST + skoff;

  int fr = lane & 15;           // m (or n) within 16-tile
  int fk = (lane >> 4) * 8;     // k offset of this quad
  int mw = (wave & 1) * 64;     // wave's 64x64 sub-tile
  int nw = (wave >> 1) * 64;

  for (int k0 = 0; k0 < K; k0 += 32) {
    uint4 a0, a1;
    if (a_fp32) {
      float4 f0 = *(const float4*)(Af + k0);
      float4 f1 = *(const float4*)(Af + k0 + 4);
      float4 f2 = *(const float4*)(Af + k0 + 8);
      float4 f3 = *(const float4*)(Af + k0 + 12);
      a0 = make_uint4(pack2bf(f0.x, f0.y), pack2bf(f0.z, f0.w),
                      pack2bf(f1.x, f1.y), pack2bf(f1.z, f1.w));
      a1 = make_uint4(pack2bf(f2.x, f2.y), pack2bf(f2.z, f2.w),
                      pack2bf(f3.x, f3.y), pack2bf(f3.z, f3.w));
    } else {
      a0 = *(const uint4*)(Ah + k0);
      a1 = *(const uint4*)(Ah + k0 + 8);
    }
    uint4 b0 = *(const uint4*)(Bp + k0);
    uint4 b1 = *(const uint4*)(Bp + k0 + 8);
    *(uint4*)AL       = a0;
    *(uint4*)(AL + 8) = a1;
    *(uint4*)BL       = b0;
    *(uint4*)(BL + 8) = b1;
    __syncthreads();

    short8 afr[4], bfr[4];
    #pragma unroll
    for (int i = 0; i < 4; ++i)
      afr[i] = *(const short8*)(Abuf + (mw + i * 16 + fr) * GST + fk);
    #pragma unroll
    for (int i = 0; i < 4; ++i)
      bfr[i] = *(const short8*)(Bbuf + (nw + i * 16 + fr) * GST + fk);
    #pragma unroll
    for (int mt = 0; mt < 4; ++mt)
      #pragma unroll
      for (int nt = 0; nt < 4; ++nt)
        acc[mt][nt] = __builtin_amdgcn_mfma_f32_16x16x32_bf16(afr[mt], bfr[nt], acc[mt][nt], 0, 0, 0);
    __syncthreads();
  }

  // D: col=lane&15, row=(lane>>4)*4+r  [m89-verified]
  int col_l = lane & 15;
  int row_b = (lane >> 4) * 4;
  #pragma unroll
  for (int mt = 0; mt < 4; ++mt)
    #pragma unroll
    for (int nt = 0; nt < 4; ++nt)
      #pragma unroll
      for (int r = 0; r < 4; ++r) {
        int m = m0 + mw + mt * 16 + row_b + r;
        if (m < M)
          C[(size_t)m * N + n0 + nw + nt * 16 + col_l] = f2bf(acc[mt][nt][r]);
      }
}

// ---------- aggregation: out[c] = sum_e norm*H[src] + (1/deg_c)*H[c] + b, relu ----------
template <int VPL>
__device__ __forceinline__ void loadbf(const unsigned short* p, float* out) {
  if constexpr (VPL == 8) {
    uint4 v = *(const uint4*)p;
    uint32_t w0 = v.x, w1 = v.y, w2 = v.z, w3 = v.w;
    out[0] = bf2f((unsigned short)(w0 & 0xffff)); out[1] = bf2f((unsigned short)(w0 >> 16));
    out[2] = bf2f((unsigned short)(w1 & 0xffff)); out[3] = bf2f((unsigned short)(w1 >> 16));
    out[4] = bf2f((unsigned short)(w2 & 0xffff)); out[5] = bf2f((unsigned short)(w2 >> 16));
    out[6] = bf2f((unsigned short)(w3 & 0xffff)); out[7] = bf2f((unsigned short)(w3 >> 16));
  } else {
    uint32_t v = *(const uint32_t*)p;
    out[0] = bf2f((unsigned short)(v & 0xffff)); out[1] = bf2f((unsigned short)(v >> 16));
  }
}

template <int F>
__global__ __launch_bounds__(256) void bgcn_aggregate(
    const unsigned short* __restrict__ H,
    const int* __restrict__ rowptr,
    const int* __restrict__ esrc,
    const float* __restrict__ enorm,
    const float* __restrict__ dis,
    const unsigned short* __restrict__ bias,
    unsigned short* __restrict__ Out,
    int n_nodes) {
  constexpr int VPL = F / 64;
  int lane = threadIdx.x & 63;
  int c = blockIdx.x * 4 + (threadIdx.x >> 6);  // one wave per node
  if (c >= n_nodes) return;
  float acc[VPL];
  #pragma unroll
  for (int j = 0; j < VPL; ++j) acc[j] = 0.0f;

  int beg = rowptr[c], end = rowptr[c + 1];
  int e = beg;
  // 4-way unroll: 4 independent row-gathers in flight per wave
  for (; e + 4 <= end; e += 4) {
    int s0 = esrc[e], s1 = esrc[e + 1], s2 = esrc[e + 2], s3 = esrc[e + 3];
    float w0 = enorm[e], w1 = enorm[e + 1], w2 = enorm[e + 2], w3 = enorm[e + 3];
    float v0[VPL], v1[VPL], v2[VPL], v3[VPL];
    loadbf<VPL>(H + (size_t)s0 * F + lane * VPL, v0);
    loadbf<VPL>(H + (size_t)s1 * F + lane * VPL, v1);
    loadbf<VPL>(H + (size_t)s2 * F + lane * VPL, v2);
    loadbf<VPL>(H + (size_t)s3 * F + lane * VPL, v3);
    #pragma unroll
    for (int j = 0; j < VPL; ++j) {
      acc[j] += w0 * v0[j];
      acc[j] += w1 * v1[j];
      acc[j] += w2 * v2[j];
      acc[j] += w3 * v3[j];
    }
  }
  for (; e < end; ++e) {
    int src = esrc[e];
    float w = enorm[e];
    float vals[VPL];
    loadbf<VPL>(H + (size_t)src * F + lane * VPL, vals);
    #pragma unroll
    for (int j = 0; j < VPL; ++j) acc[j] += w * vals[j];
  }
  float ds = dis[c];
  float wself = ds * ds;  // == 1/deg
  float vals[VPL];
  loadbf<VPL>(H + (size_t)c * F + lane * VPL, vals);
  unsigned short ob[VPL];
  #pragma unroll
  for (int j = 0; j < VPL; ++j) {
    float v = acc[j] + wself * vals[j] + bf2f(bias[lane * VPL + j]);
    ob[j] = f2bf(fmaxf(v, 0.0f));
  }
  // vectorized store
  if constexpr (VPL == 8) {
    uint4 st = make_uint4((uint32_t)ob[0] | ((uint32_t)ob[1] << 16),
                          (uint32_t)ob[2] | ((uint32_t)ob[3] << 16),
                          (uint32_t)ob[4] | ((uint32_t)ob[5] << 16),
                          (uint32_t)ob[6] | ((uint32_t)ob[7] << 16));
    *(uint4*)(Out + (size_t)c * F + lane * VPL) = st;
  } else {
    *(uint32_t*)(Out + (size_t)c * F + lane * VPL) =
        (uint32_t)ob[0] | ((uint32_t)ob[1] << 16);
  }
}

// ---------- FC(128->14) + sigmoid -> FP32 output ----------
__global__ __launch_bounds__(256) void bgcn_fc_sigmoid(
    const unsigned short* __restrict__ X,
    const unsigned short* __restrict__ W,
    const unsigned short* __restrict__ b,
    float* __restrict__ out,
    int n_nodes) {
  __shared__ float Ws[128 * 14];
  __shared__ float bs[14];
  for (int i = threadIdx.x; i < 128 * 14; i += 256) Ws[i] = bf2f(W[i]);
  if (threadIdx.x < 14) bs[threadIdx.x] = bf2f(b[threadIdx.x]);
  __syncthreads();
  int node = blockIdx.x * 256 + threadIdx.x;
  if (node >= n_nodes) return;
  float acc[14];
  #pragma unroll
  for (int c = 0; c < 14; ++c) acc[c] = bs[c];
  const unsigned short* xp = X + (size_t)node * 128;
  for (int k8 = 0; k8 < 16; ++k8) {
    float xv[8];
    loadbf<8>(xp + k8 * 8, xv);
    #pragma unroll
    for (int j = 0; j < 8; ++j) {
      int k = k8 * 8 + j;
      #pragma unroll
      for (int c = 0; c < 14; ++c) acc[c] = fmaf(xv[j], Ws[k * 14 + c], acc[c]);
    }
  }
  float* op = out + (size_t)node * 14;
  #pragma unroll
  for (int c = 0; c < 14; ++c)
    op[c] = 1.0f / (1.0f + __expf(-acc[c]));
}

// ---------- launch ----------
static inline void* wsa(char*& p, size_t bytes) {
  void* r = p;
  p += (bytes + 255) & ~(size_t)255;
  return r;
}

extern "C" void kernel_launch(void* const* d_in, const int* in_sizes, int n_in,
                              void* d_out, int out_size, void* d_ws, size_t ws_size,
                              hipStream_t stream) {
  const void* Xr   = d_in[0];   // [N,1024] fp32 (probed)
  const void* EIr  = d_in[1];   // [2,E] int64 (probed)
  const void* EWr  = d_in[2];   // [E]
  const void* W1r  = d_in[3];   // [1024,512]
  const void* b1r  = d_in[4];
  const void* W2r  = d_in[5];   // [512,128]
  const void* b2r  = d_in[6];
  const void* Wfcr = d_in[7];   // [128,14]
  const void* bfcr = d_in[8];
  float* out = (float*)d_out;   // [N,14] fp32

  const int N = in_sizes[0] / 1024;   // 50000
  const int E = in_sizes[2];          // 800000

  char* p = (char*)d_ws;
  unsigned short* bufA = (unsigned short*)wsa(p, (size_t)N * 512 * 2);  // H1; later H2+X3
  unsigned short* bufB = (unsigned short*)wsa(p, (size_t)N * 512 * 2);  // X2
  float* deg      = (float*)wsa(p, (size_t)N * 4);
  float* dis      = (float*)wsa(p, (size_t)N * 4);
  int*   counts   = (int*)wsa(p, (size_t)N * 4);
  int*   rowptr   = (int*)wsa(p, (size_t)(N + 1) * 4);
  int*   blocksum = (int*)wsa(p, 256 * 4);
  int*   fill     = (int*)wsa(p, (size_t)N * 4);
  int*   esrc     = (int*)wsa(p, (size_t)E * 4);
  float* enorm    = (float*)wsa(p, (size_t)E * 4);
  int*   eidx     = (int*)wsa(p, (size_t)2 * E * 4);
  unsigned short* ewb  = (unsigned short*)wsa(p, (size_t)E * 2);
  unsigned short* W1t  = (unsigned short*)wsa(p, (size_t)1024 * 512 * 2);  // [512][1024]
  unsigned short* W2t  = (unsigned short*)wsa(p, (size_t)512 * 128 * 2);   // [128][512]
  unsigned short* b1c  = (unsigned short*)wsa(p, 512 * 2);
  unsigned short* b2c  = (unsigned short*)wsa(p, 128 * 2);
  unsigned short* Wfcc = (unsigned short*)wsa(p, 128 * 14 * 2);
  unsigned short* bfcc = (unsigned short*)wsa(p, 16 * 2);
  int* flags      = (int*)wsa(p, 2 * 4);

  unsigned short* H1 = bufA;
  unsigned short* X2 = bufB;
  unsigned short* H2 = bufA;                       // H1 dead by then
  unsigned short* X3 = bufA + (size_t)N * 128;     // disjoint from H2

  int gN = (N + 255) / 256;
  int gE = (E + 255) / 256;

  // dtype probe + canonicalization (+ weight transpose to [N][K] bf16)
  bgcn_probe<<<1, 64, 0, stream>>>((const uint32_t*)Xr, (const uint32_t*)EIr, flags);
  bgcn_cvt_i<<<(2 * E + 255) / 256, 256, 0, stream>>>(EIr, eidx, 2 * E, flags);
  bgcn_cvt_f<<<gE, 256, 0, stream>>>(EWr, ewb, E, flags);
  bgcn_cvt_t<<<(1024 * 512 + 255) / 256, 256, 0, stream>>>(W1r, W1t, 10, 512, 1024 * 512, flags);
  bgcn_cvt_t<<<(512 * 128 + 255) / 256, 256, 0, stream>>>(W2r, W2t, 9, 128, 512 * 128, flags);
  bgcn_cvt_f<<<2, 256, 0, stream>>>(b1r, b1c, 512, flags);
  bgcn_cvt_f<<<1, 256, 0, stream>>>(b2r, b2c, 128, flags);
  bgcn_cvt_f<<<7, 256, 0, stream>>>(Wfcr, Wfcc, 128 * 14, flags);
  bgcn_cvt_f<<<1, 64, 0, stream>>>(bfcr, bfcc, 14, flags);

  const int* rowp = eidx;        // sources
  const int* colp = eidx + E;    // targets

  hipMemsetAsync(counts, 0, (size_t)N * 4, stream);
  hipMemsetAsync(fill,   0, (size_t)N * 4, stream);

  bgcn_init_deg<<<gN, 256, 0, stream>>>(deg, N);
  bgcn_deg<<<gE, 256, 0, stream>>>(colp, ewb, deg, E);
  bgcn_dis<<<gN, 256, 0, stream>>>(deg, dis, N);
  bgcn_hist<<<gE, 256, 0, stream>>>(colp, counts, E);

  int nb = (N + 1023) / 1024;
  bgcn_scan_block<<<nb, 1024, 0, stream>>>(counts, rowptr, blocksum, N);
  bgcn_scan_tops<<<1, 64, 0, stream>>>(blocksum, nb);
  bgcn_scan_add<<<nb, 1024, 0, stream>>>(rowptr, blocksum, N);
  bgcn_scatter<<<gE, 256, 0, stream>>>(rowp, colp, ewb, dis, rowptr, fill, esrc, enorm, E);

  int mblks = (N + 127) / 128;   // 391

  // layer 1: H1 = X @ W1 ; X2 = relu(agg(H1) + b1)
  bgcn_gemm128<<<mblks * 4, 256, 0, stream>>>(Xr, 1, flags, W1t, H1, N, 512, 1024, 2);
  bgcn_aggregate<512><<<(N + 3) / 4, 256, 0, stream>>>(H1, rowptr, esrc, enorm, dis, b1c, X2, N);

  // layer 2: H2 = X2 @ W2 ; X3 = relu(agg(H2) + b2)
  bgcn_gemm128<<<mblks, 256, 0, stream>>>(X2, 0, flags, W2t, H2, N, 128, 512, 0);
  bgcn_aggregate<128><<<(N + 3) / 4, 256, 0, stream>>>(H2, rowptr, esrc, enorm, dis, b2c, X3, N);

  // FC + sigmoid (fp32 out)
  bgcn_fc_sigmoid<<<gN, 256, 0, stream>>>(X3, Wfcc, bfcc, out, N);
}